// Round 15
// baseline (67.516 us; speedup 1.0000x reference)
//
#include <hip/hip_runtime.h>

#define R_ 4
#define S_ 8
#define N_ 4096
#define D_ 64
#define KS_ 128          // K per stage
#define NST_ (N_ / KS_)  // 32 stages

typedef __attribute__((ext_vector_type(8))) short bf16x8;
typedef __attribute__((ext_vector_type(4))) float f32x4;

__device__ __forceinline__ unsigned int f2bf(float f) {
    unsigned int u = __float_as_uint(f);
    return (u + 0x7FFFu + ((u >> 16) & 1u)) >> 16;   // RNE to bf16
}

// Kernel 1: ycombT[r][o][k] = bf16( coef[r] * sum_d x[r][k][d] * fc_w[r][o][d] )
__global__ __launch_bounds__(256) void prep_kernel(
    const float* __restrict__ theta, const float* __restrict__ tt,
    const float* __restrict__ x, const float* __restrict__ fc_w,
    unsigned short* __restrict__ ycombT) {
    int r  = blockIdx.x >> 6;
    int kb = blockIdx.x & 63;
    int tid = threadIdx.x;

    __shared__ float xs[64][64];
    __shared__ float ws[64][65];

    const float* xp = x    + ((size_t)r * N_ + (size_t)kb * 64) * D_;
    const float* wp = fc_w + (size_t)r * D_ * D_;
    for (int i = 0; i < 16; ++i) {
        int flat = i * 256 + tid;
        xs[flat >> 6][flat & 63] = xp[flat];
        ws[flat >> 6][flat & 63] = wp[flat];
    }
    float coef = 0.f;
#pragma unroll
    for (int s = 0; s < S_; ++s) coef += theta[r * S_ + s] * tt[r * S_ + s];
    __syncthreads();

    int o = tid & 63, kg = tid >> 6;
    for (int kl = kg; kl < 64; kl += 4) {
        float dot = 0.f;
#pragma unroll
        for (int d = 0; d < D_; ++d) dot += xs[kl][d] * ws[o][d];
        ycombT[(size_t)(r * D_ + o) * N_ + (size_t)kb * 64 + kl] =
            (unsigned short)f2bf(coef * dot);
    }
}

// Kernel 2: R9's exact schedule (dense 2-row x 512B A bursts, dbuf A/B,
// compute -> bar -> write(other buf) -> prefetch-issue -> bar) with T4
// counted barriers: lgkmcnt(0)-only + raw s_barrier in the main loop, so
// the stage s+2 prefetch stays in flight across barrier 2 and overlaps the
// next stage's compute instead of being drained by vmcnt(0).
__global__ __launch_bounds__(512) void gemm_kernel(
    const float* __restrict__ a, const unsigned short* __restrict__ ycombT,
    const float* __restrict__ fc_b, const float* __restrict__ alpha0p,
    float* __restrict__ out) {
    int bid = blockIdx.x;             // 1024 blocks
    int r   = bid & 3;
    int rb  = bid >> 2;               // 64-row tile index
    int tid  = threadIdx.x;
    int wave = tid >> 6;
    int wm   = wave & 3;              // 16-row group
    int wk   = wave >> 2;             // 64-k half per stage
    int lane = tid & 63;
    int l15  = lane & 15;
    int kg   = lane >> 4;

    // pool: [A0:16K][A1:16K][B0:16K][B1:16K]; red overlays after the loop
    __shared__ __align__(16) char pool[65536];
#define AB(buf) ((buf) * 16384)
#define BB(buf) (32768 + (buf) * 16384)

    // ---- A staging: thread covers rows 16j + tr (j=0..3), tr=tid>>5;
    // floats (tid&31)*4 -> per inst a wave reads 2 rows x 512B dense.
    int tr    = tid >> 5;              // 0..15
    int ak    = (tid & 31) * 4;
    int agran = (tid & 31) >> 1;       // 16B granule (0..15)
    int ahalf = tid & 1;
    int swzA  = (tr & 7) << 1;
    const float* asrc = a + ((size_t)(r * N_ + rb * 64)) * N_;

    // ---- B staging: thread -> o-row tid>>3, granules g2,g2+1 (16B)
    int srow = tid >> 3, g2 = (tid & 7) * 2;
    int swzB = (srow & 7) << 1;
    const unsigned short* ysrc = ycombT + (size_t)(r * D_ + srow) * N_ + g2 * 8;

    int swzr = (l15 & 7) << 1;         // read-side XOR (A and B share it)

    f32x4 acc0 = {0.f, 0.f, 0.f, 0.f};
    f32x4 acc1 = {0.f, 0.f, 0.f, 0.f};
    f32x4 acc2 = {0.f, 0.f, 0.f, 0.f};
    f32x4 acc3 = {0.f, 0.f, 0.f, 0.f};

    float4 an[4];
    uint4  bv0, bv1;

    auto loadA = [&](int s) {
#pragma unroll
        for (int j = 0; j < 4; ++j)
            an[j] = *(const float4*)(asrc + (size_t)(16 * j + tr) * N_
                                          + (size_t)s * KS_ + ak);
    };
    auto loadB = [&](int s) {
        bv0 = *(const uint4*)(ysrc + (size_t)s * KS_);
        bv1 = *(const uint4*)(ysrc + (size_t)s * KS_ + 8);
    };
    auto writeA = [&](int buf) {
#pragma unroll
        for (int j = 0; j < 4; ++j) {
            int row = 16 * j + tr;
            uint2 p;
            p.x = (f2bf(an[j].y) << 16) | f2bf(an[j].x);
            p.y = (f2bf(an[j].w) << 16) | f2bf(an[j].z);
            *(uint2*)(pool + AB(buf) + row * 256
                      + ((agran ^ swzA) << 4) + (ahalf << 3)) = p;
        }
    };
    auto writeB = [&](int buf) {
        *(uint4*)(pool + BB(buf) + srow * 256 + (((g2    ) ^ swzB) << 4)) = bv0;
        *(uint4*)(pool + BB(buf) + srow * 256 + (((g2 + 1) ^ swzB) << 4)) = bv1;
    };
    auto compute = [&](int buf) {
#pragma unroll
        for (int st = 0; st < 2; ++st) {
            int slot = ((wk * 8 + st * 4 + kg) ^ swzr) << 4;
            bf16x8 af = *(const bf16x8*)(pool + AB(buf) + (wm * 16 + l15) * 256 + slot);
            bf16x8 b0 = *(const bf16x8*)(pool + BB(buf) + ( 0 + l15) * 256 + slot);
            bf16x8 b1 = *(const bf16x8*)(pool + BB(buf) + (16 + l15) * 256 + slot);
            bf16x8 b2 = *(const bf16x8*)(pool + BB(buf) + (32 + l15) * 256 + slot);
            bf16x8 b3 = *(const bf16x8*)(pool + BB(buf) + (48 + l15) * 256 + slot);
            acc0 = __builtin_amdgcn_mfma_f32_16x16x32_bf16(af, b0, acc0, 0, 0, 0);
            acc1 = __builtin_amdgcn_mfma_f32_16x16x32_bf16(af, b1, acc1, 0, 0, 0);
            acc2 = __builtin_amdgcn_mfma_f32_16x16x32_bf16(af, b2, acc2, 0, 0, 0);
            acc3 = __builtin_amdgcn_mfma_f32_16x16x32_bf16(af, b3, acc3, 0, 0, 0);
        }
    };

    // counted barrier: LDS-visibility only, no vmcnt drain
    auto cbar = []() {
        asm volatile("s_waitcnt lgkmcnt(0)" ::: "memory");
        __builtin_amdgcn_s_barrier();
    };

    // prologue: stage 0 -> LDS buf0; stage 1 raw -> regs
    loadA(0); loadB(0);
    writeA(0); writeB(0);
    loadA(1); loadB(1);
    __syncthreads();

    for (int s = 0; s < NST_; ++s) {
        int buf = s & 1;
        compute(buf);
        cbar();                                  // reads of buf done (lgkm only)
        if (s + 1 < NST_) {
            writeA(buf ^ 1); writeB(buf ^ 1);    // regs -> other buf
            if (s + 2 < NST_) { loadA(s + 2); loadB(s + 2); }   // issue prefetch
            cbar();                              // writes visible; prefetch stays in flight
        }
    }

    // wk-reduction + epilogue (red overlays pool). C/D: col=c*16+l15, rloc=kg*4+j.
    float (*red)[16][65] = (float (*)[16][65])pool;
    if (wk == 1) {
#pragma unroll
        for (int c = 0; c < 4; ++c) {
            f32x4 acc = (c == 0) ? acc0 : (c == 1) ? acc1 : (c == 2) ? acc2 : acc3;
#pragma unroll
            for (int j = 0; j < 4; ++j)
                red[wm][kg * 4 + j][c * 16 + l15] = acc[j];
        }
    }
    __syncthreads();
    if (wk == 0) {
        const float alpha0 = *alpha0p;
        const size_t diff_off = (size_t)R_ * N_ * D_;   // out = [latent | diffusions]
#pragma unroll
        for (int c = 0; c < 4; ++c) {
            f32x4 acc = (c == 0) ? acc0 : (c == 1) ? acc1 : (c == 2) ? acc2 : acc3;
            int col = c * 16 + l15;
            float b = fc_b[r * D_ + col];
#pragma unroll
            for (int j = 0; j < 4; ++j) {
                int rloc = kg * 4 + j;
                float v = acc[j] + red[wm][rloc][col] + b;
                v = (v >= 0.f) ? v : alpha0 * v;
                out[diff_off + ((size_t)(r * N_ + rb * 64 + wm * 16 + rloc)) * D_ + col] = v;
            }
        }
    }
}

// Kernel 3: 1x1 conv over relation channels + PReLU.
__global__ __launch_bounds__(256) void conv_kernel(
    const float* __restrict__ conv_w, const float* __restrict__ conv_b,
    const float* __restrict__ alpha1p, float* __restrict__ out) {
    const size_t nd = (size_t)N_ * D_;
    const size_t diff_off = (size_t)R_ * nd;
    size_t i = ((size_t)blockIdx.x * 256 + threadIdx.x) * 4;

    float4 d0 = *(const float4*)(out + diff_off + 0 * nd + i);
    float4 d1 = *(const float4*)(out + diff_off + 1 * nd + i);
    float4 d2 = *(const float4*)(out + diff_off + 2 * nd + i);
    float4 d3 = *(const float4*)(out + diff_off + 3 * nd + i);
    const float alpha1 = *alpha1p;
#pragma unroll
    for (int s = 0; s < R_; ++s) {
        float w0 = conv_w[s * R_ + 0], w1 = conv_w[s * R_ + 1];
        float w2 = conv_w[s * R_ + 2], w3 = conv_w[s * R_ + 3];
        float cb = conv_b[s];
        float4 v;
        v.x = cb + w0 * d0.x + w1 * d1.x + w2 * d2.x + w3 * d3.x;
        v.y = cb + w0 * d0.y + w1 * d1.y + w2 * d2.y + w3 * d3.y;
        v.z = cb + w0 * d0.z + w1 * d1.z + w2 * d2.z + w3 * d3.z;
        v.w = cb + w0 * d0.w + w1 * d1.w + w2 * d2.w + w3 * d3.w;
        v.x = (v.x >= 0.f) ? v.x : alpha1 * v.x;
        v.y = (v.y >= 0.f) ? v.y : alpha1 * v.y;
        v.z = (v.z >= 0.f) ? v.z : alpha1 * v.z;
        v.w = (v.w >= 0.f) ? v.w : alpha1 * v.w;
        *(float4*)(out + s * nd + i) = v;
    }
}

extern "C" void kernel_launch(void* const* d_in, const int* in_sizes, int n_in,
                              void* d_out, int out_size, void* d_ws, size_t ws_size,
                              hipStream_t stream) {
    const float* theta  = (const float*)d_in[0];
    const float* tt     = (const float*)d_in[1];
    const float* a      = (const float*)d_in[2];
    const float* x      = (const float*)d_in[3];
    const float* fc_w   = (const float*)d_in[4];
    const float* fc_b   = (const float*)d_in[5];
    const float* conv_w = (const float*)d_in[6];
    const float* conv_b = (const float*)d_in[7];
    const float* alpha0 = (const float*)d_in[8];
    const float* alpha1 = (const float*)d_in[9];
    float* out = (float*)d_out;
    unsigned short* ycombT = (unsigned short*)d_ws;   // 2 MiB bf16

    prep_kernel<<<dim3(R_ * (N_ / 64)), dim3(256), 0, stream>>>(theta, tt, x, fc_w, ycombT);
    gemm_kernel<<<dim3((N_ / 64) * R_), dim3(512), 0, stream>>>(a, ycombT, fc_b, alpha0, out);
    conv_kernel<<<dim3((N_ * D_) / 4 / 256), dim3(256), 0, stream>>>(conv_w, conv_b, alpha1, out);
}

// Round 16
// 59.932 us; speedup vs baseline: 1.1265x; 1.1265x over previous
//
#include <hip/hip_runtime.h>

#define R_ 4
#define S_ 8
#define N_ 4096
#define D_ 64
#define KS_ 128          // K per stage
#define NST_ (N_ / KS_)  // 32 stages

typedef __attribute__((ext_vector_type(8))) short bf16x8;
typedef __attribute__((ext_vector_type(4))) float f32x4;

__device__ __forceinline__ unsigned int f2bf(float f) {
    unsigned int u = __float_as_uint(f);
    return (u + 0x7FFFu + ((u >> 16) & 1u)) >> 16;   // RNE to bf16
}

// Kernel 1: ycombT[r][o][k] = bf16( coef[r] * sum_d x[r][k][d] * fc_w[r][o][d] )
__global__ __launch_bounds__(256) void prep_kernel(
    const float* __restrict__ theta, const float* __restrict__ tt,
    const float* __restrict__ x, const float* __restrict__ fc_w,
    unsigned short* __restrict__ ycombT) {
    int r  = blockIdx.x >> 6;
    int kb = blockIdx.x & 63;
    int tid = threadIdx.x;

    __shared__ float xs[64][64];
    __shared__ float ws[64][65];

    const float* xp = x    + ((size_t)r * N_ + (size_t)kb * 64) * D_;
    const float* wp = fc_w + (size_t)r * D_ * D_;
    for (int i = 0; i < 16; ++i) {
        int flat = i * 256 + tid;
        xs[flat >> 6][flat & 63] = xp[flat];
        ws[flat >> 6][flat & 63] = wp[flat];
    }
    float coef = 0.f;
#pragma unroll
    for (int s = 0; s < S_; ++s) coef += theta[r * S_ + s] * tt[r * S_ + s];
    __syncthreads();

    int o = tid & 63, kg = tid >> 6;
    for (int kl = kg; kl < 64; kl += 4) {
        float dot = 0.f;
#pragma unroll
        for (int d = 0; d < D_; ++d) dot += xs[kl][d] * ws[o][d];
        ycombT[(size_t)(r * D_ + o) * N_ + (size_t)kb * 64 + kl] =
            (unsigned short)f2bf(coef * dot);
    }
}

// Kernel 2 (R9, best measured: 58.8 us total): block = (r, 64 rows), full K,
// 8 waves wm x wk. A staged through LDS with DENSE loads (one inst = 2 rows
// x 512B contiguous), B shared by the block. Both tiles [64][128] bf16,
// XOR-swizzled 16B granules, double-buffered, 2 barriers/stage.
__global__ __launch_bounds__(512) void gemm_kernel(
    const float* __restrict__ a, const unsigned short* __restrict__ ycombT,
    const float* __restrict__ fc_b, const float* __restrict__ alpha0p,
    float* __restrict__ out) {
    int bid = blockIdx.x;             // 256 blocks
    int r   = bid & 3;
    int rb  = bid >> 2;               // 64-row tile index
    int tid  = threadIdx.x;
    int wave = tid >> 6;
    int wm   = wave & 3;              // 16-row group
    int wk   = wave >> 2;             // 64-k half per stage
    int lane = tid & 63;
    int l15  = lane & 15;
    int kg   = lane >> 4;

    // pool: [A0:0-16K][A1:16-32K][B0:32-48K][B1:48-64K]; red overlays at end
    __shared__ __align__(16) char pool[65536];
#define ABASE(buf) ((buf) * 16384)
#define BBASE(buf) (32768 + (buf) * 16384)

    // ---- A staging map (dense): thread t covers rows {j*16 + (t>>5)},
    // floats k0=(t&31)*4 .. +3 of the 128-wide stage tile.
    int arow_loc = tid >> 5;               // 0..15
    int ak       = (tid & 31) * 4;         // float offset in stage tile
    int agran    = (tid & 31) >> 1;        // 16B granule
    int ahalf    = tid & 1;                // 8B half of granule
    int swzA     = (arow_loc & 7) << 1;    // rowj&7 == arow_loc&7 (j*16 = 0 mod 8)
    const float* asrc = a + ((size_t)(r * N_ + rb * 64)) * N_;

    // ---- B staging map: thread -> o-row tid>>3, granules g2, g2+1
    int srow = tid >> 3, g2 = (tid & 7) * 2;
    int swzB = (srow & 7) << 1;
    const unsigned short* ysrc = ycombT + (size_t)(r * D_ + srow) * N_ + g2 * 8;

    // ---- frag read slots (both A and B share the k-granule layout)
    int swzr = (l15 & 7) << 1;

    f32x4 acc0 = {0.f, 0.f, 0.f, 0.f};
    f32x4 acc1 = {0.f, 0.f, 0.f, 0.f};
    f32x4 acc2 = {0.f, 0.f, 0.f, 0.f};
    f32x4 acc3 = {0.f, 0.f, 0.f, 0.f};

    float4 an[4];
    uint4  bv0, bv1;

    auto loadA = [&](int s) {
#pragma unroll
        for (int j = 0; j < 4; ++j)
            an[j] = *(const float4*)(asrc + (size_t)(j * 16 + arow_loc) * N_
                                          + (size_t)s * KS_ + ak);
    };
    auto loadB = [&](int s) {
        bv0 = *(const uint4*)(ysrc + (size_t)s * KS_);
        bv1 = *(const uint4*)(ysrc + (size_t)s * KS_ + 8);
    };
    auto writeA = [&](int buf) {
#pragma unroll
        for (int j = 0; j < 4; ++j) {
            int rowj = j * 16 + arow_loc;
            uint2 p;
            p.x = (f2bf(an[j].y) << 16) | f2bf(an[j].x);
            p.y = (f2bf(an[j].w) << 16) | f2bf(an[j].z);
            *(uint2*)(pool + ABASE(buf) + rowj * 256
                      + ((agran ^ swzA) << 4) + (ahalf << 3)) = p;
        }
    };
    auto writeB = [&](int buf) {
        *(uint4*)(pool + BBASE(buf) + srow * 256 + (((g2    ) ^ swzB) << 4)) = bv0;
        *(uint4*)(pool + BBASE(buf) + srow * 256 + (((g2 + 1) ^ swzB) << 4)) = bv1;
    };
    auto compute = [&](int buf) {
#pragma unroll
        for (int step = 0; step < 2; ++step) {
            int slot = (((wk * 8 + step * 4 + kg) ^ swzr)) << 4;
            bf16x8 af = *(const bf16x8*)(pool + ABASE(buf) + (wm * 16 + l15) * 256 + slot);
            bf16x8 b0 = *(const bf16x8*)(pool + BBASE(buf) + ( 0 + l15) * 256 + slot);
            bf16x8 b1 = *(const bf16x8*)(pool + BBASE(buf) + (16 + l15) * 256 + slot);
            bf16x8 b2 = *(const bf16x8*)(pool + BBASE(buf) + (32 + l15) * 256 + slot);
            bf16x8 b3 = *(const bf16x8*)(pool + BBASE(buf) + (48 + l15) * 256 + slot);
            acc0 = __builtin_amdgcn_mfma_f32_16x16x32_bf16(af, b0, acc0, 0, 0, 0);
            acc1 = __builtin_amdgcn_mfma_f32_16x16x32_bf16(af, b1, acc1, 0, 0, 0);
            acc2 = __builtin_amdgcn_mfma_f32_16x16x32_bf16(af, b2, acc2, 0, 0, 0);
            acc3 = __builtin_amdgcn_mfma_f32_16x16x32_bf16(af, b3, acc3, 0, 0, 0);
        }
    };

    // prologue: stage 0 -> LDS buf0; stage 1 raw -> regs
    loadA(0); loadB(0);
    writeA(0); writeB(0);
    loadA(1); loadB(1);
    __syncthreads();

#pragma unroll 2
    for (int s = 0; s < NST_; ++s) {
        int buf = s & 1;
        compute(buf);
        __syncthreads();                       // all reads of buf done
        if (s + 1 < NST_) {
            writeA(buf ^ 1); writeB(buf ^ 1);  // stage s+1 into other buffer
            if (s + 2 < NST_) { loadA(s + 2); loadB(s + 2); }
            __syncthreads();                   // writes visible before next compute
        }
    }

    // wk-reduction + epilogue (red overlays pool; all LDS dead after last barrier)
    float (*red)[16][65] = (float (*)[16][65])pool;
    if (wk == 1) {
#pragma unroll
        for (int c = 0; c < 4; ++c) {
            f32x4 acc = (c == 0) ? acc0 : (c == 1) ? acc1 : (c == 2) ? acc2 : acc3;
#pragma unroll
            for (int j = 0; j < 4; ++j)
                red[wm][kg * 4 + j][c * 16 + l15] = acc[j];
        }
    }
    __syncthreads();
    if (wk == 0) {
        const float alpha0 = *alpha0p;
        const size_t diff_off = (size_t)R_ * N_ * D_;   // out = [latent | diffusions]
#pragma unroll
        for (int c = 0; c < 4; ++c) {
            f32x4 acc = (c == 0) ? acc0 : (c == 1) ? acc1 : (c == 2) ? acc2 : acc3;
            int col = c * 16 + l15;
            float b = fc_b[r * D_ + col];
#pragma unroll
            for (int j = 0; j < 4; ++j) {
                int rloc = kg * 4 + j;
                float v = acc[j] + red[wm][rloc][col] + b;
                v = (v >= 0.f) ? v : alpha0 * v;
                out[diff_off + ((size_t)(r * N_ + rb * 64 + wm * 16 + rloc)) * D_ + col] = v;
            }
        }
    }
}

// Kernel 3: 1x1 conv over relation channels + PReLU.
__global__ __launch_bounds__(256) void conv_kernel(
    const float* __restrict__ conv_w, const float* __restrict__ conv_b,
    const float* __restrict__ alpha1p, float* __restrict__ out) {
    const size_t nd = (size_t)N_ * D_;
    const size_t diff_off = (size_t)R_ * nd;
    size_t i = ((size_t)blockIdx.x * 256 + threadIdx.x) * 4;

    float4 d0 = *(const float4*)(out + diff_off + 0 * nd + i);
    float4 d1 = *(const float4*)(out + diff_off + 1 * nd + i);
    float4 d2 = *(const float4*)(out + diff_off + 2 * nd + i);
    float4 d3 = *(const float4*)(out + diff_off + 3 * nd + i);
    const float alpha1 = *alpha1p;
#pragma unroll
    for (int s = 0; s < R_; ++s) {
        float w0 = conv_w[s * R_ + 0], w1 = conv_w[s * R_ + 1];
        float w2 = conv_w[s * R_ + 2], w3 = conv_w[s * R_ + 3];
        float cb = conv_b[s];
        float4 v;
        v.x = cb + w0 * d0.x + w1 * d1.x + w2 * d2.x + w3 * d3.x;
        v.y = cb + w0 * d0.y + w1 * d1.y + w2 * d2.y + w3 * d3.y;
        v.z = cb + w0 * d0.z + w1 * d1.z + w2 * d2.z + w3 * d3.z;
        v.w = cb + w0 * d0.w + w1 * d1.w + w2 * d2.w + w3 * d3.w;
        v.x = (v.x >= 0.f) ? v.x : alpha1 * v.x;
        v.y = (v.y >= 0.f) ? v.y : alpha1 * v.y;
        v.z = (v.z >= 0.f) ? v.z : alpha1 * v.z;
        v.w = (v.w >= 0.f) ? v.w : alpha1 * v.w;
        *(float4*)(out + s * nd + i) = v;
    }
}

extern "C" void kernel_launch(void* const* d_in, const int* in_sizes, int n_in,
                              void* d_out, int out_size, void* d_ws, size_t ws_size,
                              hipStream_t stream) {
    const float* theta  = (const float*)d_in[0];
    const float* tt     = (const float*)d_in[1];
    const float* a      = (const float*)d_in[2];
    const float* x      = (const float*)d_in[3];
    const float* fc_w   = (const float*)d_in[4];
    const float* fc_b   = (const float*)d_in[5];
    const float* conv_w = (const float*)d_in[6];
    const float* conv_b = (const float*)d_in[7];
    const float* alpha0 = (const float*)d_in[8];
    const float* alpha1 = (const float*)d_in[9];
    float* out = (float*)d_out;
    unsigned short* ycombT = (unsigned short*)d_ws;   // 2 MiB bf16

    prep_kernel<<<dim3(R_ * (N_ / 64)), dim3(256), 0, stream>>>(theta, tt, x, fc_w, ycombT);
    gemm_kernel<<<dim3((N_ / 64) * R_), dim3(512), 0, stream>>>(a, ycombT, fc_b, alpha0, out);
    conv_kernel<<<dim3((N_ * D_) / 4 / 256), dim3(256), 0, stream>>>(conv_w, conv_b, alpha1, out);
}